// Round 2
// baseline (2135.280 us; speedup 1.0000x reference)
//
#include <hip/hip_runtime.h>
#include <hip/hip_bf16.h>
#include <cstddef>

// ModulatedConv2d (StyleGAN2-style) for B=8, I=O=256, H=W=128, K=3, PAD=1, SD=512.
// Plan: tiny kernel1 (style modulation s = style@mod_w.T + mod_b),
//       tiny kernel2 (demod[b][o] = SCALE*rsqrt(SCALE^2*sum_i s_i^2*sum_k w^2 + eps)),
//       big kernel3: implicit-GEMM conv with bf16 MFMA 16x16x32, f32 accum,
//       fused LeakyReLU(0.2).

#define IN_C 256
#define OUT_C 256
#define HW 16384
#define SDIM 512
#define SCALE_F 0.020833333333333332f  // 1/sqrt(256*9) = 1/48
#define EPS_F 1e-8f
#define NEG_SLOPE 0.2f

typedef short bf16x8 __attribute__((ext_vector_type(8)));
typedef float f32x4 __attribute__((ext_vector_type(4)));

__device__ inline unsigned short f2bf(float f) {
  unsigned u = __builtin_bit_cast(unsigned, f);
  unsigned r = u + 0x7FFFu + ((u >> 16) & 1u);
  return (unsigned short)(r >> 16);
}

// ---------------- kernel 1: s[b][i] = dot(style[b], mod_w[i]) + mod_b[i] ----
__global__ void style_mod_kernel(const float* __restrict__ style,
                                 const float* __restrict__ mod_w,
                                 const float* __restrict__ mod_b,
                                 float* __restrict__ s_out) {
  int b = blockIdx.x;
  int i = threadIdx.x;  // 256 threads
  const float* st = style + (size_t)b * SDIM;
  const float* mw = mod_w + (size_t)i * SDIM;
  float acc = 0.f;
#pragma unroll 8
  for (int j = 0; j < SDIM; ++j) acc += st[j] * mw[j];
  s_out[b * IN_C + i] = acc + mod_b[i];
}

// ---------------- kernel 2: dscaled[b][o] = SCALE * rsqrt(SCALE^2*T + eps) --
// T = sum_i s[b][i]^2 * sum_k weight[o][i][k]^2
__global__ void demod_kernel(const float* __restrict__ weight,
                             const float* __restrict__ s_in,
                             float* __restrict__ dscaled) {
  int bo = blockIdx.x;           // b*256 + o
  int b = bo >> 8, o = bo & 255;
  int i = threadIdx.x;           // 256 threads, one per input channel
  const float* wp = weight + ((size_t)o * IN_C + i) * 9;
  float wsum = 0.f;
#pragma unroll
  for (int k = 0; k < 9; ++k) wsum += wp[k] * wp[k];
  float sv = s_in[b * IN_C + i];
  float v = sv * sv * wsum;
  // wave64 reduce
#pragma unroll
  for (int off = 32; off > 0; off >>= 1) v += __shfl_down(v, off);
  __shared__ float red[4];
  int lane = threadIdx.x & 63, wv = threadIdx.x >> 6;
  if (lane == 0) red[wv] = v;
  __syncthreads();
  if (threadIdx.x == 0) {
    float t = red[0] + red[1] + red[2] + red[3];
    dscaled[bo] = SCALE_F * rsqrtf(SCALE_F * SCALE_F * t + EPS_F);
  }
}

// ---------------- kernel 3: implicit-GEMM conv + leaky relu -----------------
// grid: (HW/64, OUT_C/64, B); block: 256 (4 waves as 2x2).
// Per block: output tile 64 o-rows x 64 pixels (one image row segment).
// K-loop: (kh,kw) x (I in tiles of 32).
#define ASTR 40  // LDS row stride in bf16 elems: 80B, keeps 16B alignment

__global__ __launch_bounds__(256) void modconv_kernel(
    const float* __restrict__ x, const float* __restrict__ weight,
    const float* __restrict__ s_in, const float* __restrict__ dscaled,
    float* __restrict__ out) {
  __shared__ __align__(16) short As[64 * ASTR];
  __shared__ __align__(16) short Xs[64 * ASTR];

  const int tid = threadIdx.x;
  const int lane = tid & 63;
  const int wv = tid >> 6;
  const int wr = wv >> 1;   // wave row (0..1) -> o dim
  const int wc = wv & 1;    // wave col (0..1) -> pixel dim
  const int b = blockIdx.z;
  const int o0 = blockIdx.y * 64;
  const int p0 = blockIdx.x * 64;
  const int h = p0 >> 7;          // W=128 -> 2 pixel-tiles per image row
  const int w0 = p0 & 127;

  f32x4 acc[2][2] = {};

  const float* sb = s_in + b * IN_C;
  const float* db = dscaled + b * OUT_C + o0;
  const float* xb = x + (size_t)b * IN_C * HW;

  for (int kh = 0; kh < 3; ++kh) {
    const int hh = h + kh - 1;
    const bool vh = ((unsigned)hh < 128u);
    for (int kw = 0; kw < 3; ++kw) {
      for (int i0 = 0; i0 < IN_C; i0 += 32) {
        // ---- stage A tile: As[oo][ii] = weight[o0+oo][i0+ii][kh][kw]*s*dmod
#pragma unroll
        for (int r = 0; r < 8; ++r) {
          int f = r * 256 + tid;
          int oo = f >> 5, iil = f & 31;
          float wval =
              weight[((size_t)(o0 + oo) * IN_C + (i0 + iil)) * 9 + kh * 3 + kw];
          float a = wval * sb[i0 + iil] * db[oo];
          As[oo * ASTR + iil] = (short)f2bf(a);
        }
        // ---- stage X tile transposed: Xs[nn][ii] = x[i0+ii][hh][w0+nn+kw-1]
#pragma unroll
        for (int r = 0; r < 8; ++r) {
          int f = r * 256 + tid;
          int ii = f >> 6, nn = f & 63;
          int ww = w0 + nn + kw - 1;
          float v = 0.f;
          if (vh && (unsigned)ww < 128u)
            v = xb[(size_t)(i0 + ii) * HW + hh * 128 + ww];
          Xs[nn * ASTR + ii] = (short)f2bf(v);
        }
        __syncthreads();
        // ---- fragments + MFMA
        const int k8 = (lane >> 4) * 8;
        const int arow = wr * 32 + (lane & 15);
        const int brow = wc * 32 + (lane & 15);
        bf16x8 a0 = *(const bf16x8*)&As[arow * ASTR + k8];
        bf16x8 a1 = *(const bf16x8*)&As[(arow + 16) * ASTR + k8];
        bf16x8 b0 = *(const bf16x8*)&Xs[brow * ASTR + k8];
        bf16x8 b1 = *(const bf16x8*)&Xs[(brow + 16) * ASTR + k8];
        acc[0][0] = __builtin_amdgcn_mfma_f32_16x16x32_bf16(a0, b0, acc[0][0], 0, 0, 0);
        acc[0][1] = __builtin_amdgcn_mfma_f32_16x16x32_bf16(a0, b1, acc[0][1], 0, 0, 0);
        acc[1][0] = __builtin_amdgcn_mfma_f32_16x16x32_bf16(a1, b0, acc[1][0], 0, 0, 0);
        acc[1][1] = __builtin_amdgcn_mfma_f32_16x16x32_bf16(a1, b1, acc[1][1], 0, 0, 0);
        __syncthreads();
      }
    }
  }

  // ---- epilogue: leaky relu + store
  float* ob = out + (((size_t)b * OUT_C + o0) << 14) + p0;
  const int colp = lane & 15;
  const int rq = lane >> 4;
#pragma unroll
  for (int m = 0; m < 2; ++m)
#pragma unroll
    for (int n = 0; n < 2; ++n)
#pragma unroll
      for (int r = 0; r < 4; ++r) {
        int orow = wr * 32 + m * 16 + rq * 4 + r;
        int pcol = wc * 32 + n * 16 + colp;
        float v = acc[m][n][r];
        v = (v >= 0.f) ? v : NEG_SLOPE * v;
        ob[((size_t)orow << 14) + pcol] = v;
      }
}

// ---------------- launcher ---------------------------------------------------
extern "C" void kernel_launch(void* const* d_in, const int* in_sizes, int n_in,
                              void* d_out, int out_size, void* d_ws,
                              size_t ws_size, hipStream_t stream) {
  const float* x = (const float*)d_in[0];      // [8,256,128,128]
  const float* style = (const float*)d_in[1];  // [8,512]
  const float* weight = (const float*)d_in[2]; // [256,256,3,3]
  const float* mod_w = (const float*)d_in[3];  // [256,512]
  const float* mod_b = (const float*)d_in[4];  // [256]
  float* out = (float*)d_out;                  // [8,256,128,128]

  float* s_ws = (float*)d_ws;                  // [8*256]
  float* d_ws_f = s_ws + 8 * IN_C;             // [8*256] scaled demod

  style_mod_kernel<<<dim3(8), dim3(256), 0, stream>>>(style, mod_w, mod_b, s_ws);
  demod_kernel<<<dim3(8 * OUT_C), dim3(256), 0, stream>>>(weight, s_ws, d_ws_f);

  dim3 grid(HW / 64, OUT_C / 64, 8);
  modconv_kernel<<<grid, dim3(256), 0, stream>>>(x, weight, s_ws, d_ws_f, out);
}

// Round 4
// 407.344 us; speedup vs baseline: 5.2420x; 5.2420x over previous
//
#include <hip/hip_runtime.h>
#include <hip/hip_bf16.h>
#include <cstddef>
#include <cstdint>

// ModulatedConv2d: B=8, I=O=256, H=W=128, K=3, PAD=1, SD=512.
// y[b,o,p] = leaky( dscaled[b,o] * sum_{kh,kw,i} w[o,i,kh,kw] * (x*s)[b,i,p'] )
// Pipeline: style -> demod -> wpack (bf16 swizzled tiles) & xpack (bf16(x*s),
// swizzled, zero guard cols) -> MFMA implicit-GEMM conv (global_load_lds
// staging, swizzled ds_read_b128 fragments, fused demod+LeakyReLU epilogue).
// Workspace use: 16 KB (s, dscaled) + 1.125 MB (Wbf) + 65 MB (X') ~= 69.4 MB.

#define IN_C 256
#define OUT_C 256
#define HW 16384
#define W_IMG 128
#define SDIM 512
#define SCALE_F 0.020833333333333332f  // 1/48
#define EPS_F 1e-8f
#define NEG_SLOPE 0.2f

#define XROWB 8320   // per (b,iblk,row): 130 slots * 32 i * 2B
#define WTILEB 8192  // per (tap,oblk,iblk): 128 o * 32 i * 2B

typedef short bf16x8 __attribute__((ext_vector_type(8)));
typedef float f32x4 __attribute__((ext_vector_type(4)));

__device__ __forceinline__ unsigned short f2bf(float f) {
  unsigned u = __builtin_bit_cast(unsigned, f);
  unsigned r = u + 0x7FFFu + ((u >> 16) & 1u);
  return (unsigned short)(r >> 16);
}

__device__ __forceinline__ void glds16(const void* g, void* l) {
  __builtin_amdgcn_global_load_lds(
      (const __attribute__((address_space(1))) unsigned int*)g,
      (__attribute__((address_space(3))) unsigned int*)l, 16, 0, 0);
}

// ---- kernel 1: s[b][i] = style[b] . mod_w[i] + mod_b[i] --------------------
__global__ void style_mod_kernel(const float* __restrict__ style,
                                 const float* __restrict__ mod_w,
                                 const float* __restrict__ mod_b,
                                 float* __restrict__ s_out) {
  int b = blockIdx.x;
  int i = threadIdx.x;  // 256 threads
  const float* st = style + (size_t)b * SDIM;
  const float* mw = mod_w + (size_t)i * SDIM;
  float acc = 0.f;
#pragma unroll 8
  for (int j = 0; j < SDIM; ++j) acc += st[j] * mw[j];
  s_out[b * IN_C + i] = acc + mod_b[i];
}

// ---- kernel 2: dscaled[b][o] = SCALE * rsqrt(SCALE^2*T + eps) --------------
__global__ void demod_kernel(const float* __restrict__ weight,
                             const float* __restrict__ s_in,
                             float* __restrict__ dscaled) {
  int bo = blockIdx.x;  // b*256 + o
  int b = bo >> 8, o = bo & 255;
  int i = threadIdx.x;
  const float* wp = weight + ((size_t)o * IN_C + i) * 9;
  float wsum = 0.f;
#pragma unroll
  for (int k = 0; k < 9; ++k) wsum += wp[k] * wp[k];
  float sv = s_in[b * IN_C + i];
  float v = sv * sv * wsum;
#pragma unroll
  for (int off = 32; off > 0; off >>= 1) v += __shfl_down(v, off);
  __shared__ float red[4];
  int lane = threadIdx.x & 63, wv = threadIdx.x >> 6;
  if (lane == 0) red[wv] = v;
  __syncthreads();
  if (threadIdx.x == 0) {
    float t = red[0] + red[1] + red[2] + red[3];
    dscaled[bo] = SCALE_F * rsqrtf(SCALE_F * SCALE_F * t + EPS_F);
  }
}

// ---- kernel 3: pack W -> bf16 swizzled tiles [tap][oblk2][iblk8][128][32] --
__global__ void wpack_kernel(const float* __restrict__ weight,
                             unsigned char* __restrict__ wbf) {
  int tap = blockIdx.x, oblk = blockIdx.y, iblk = blockIdx.z;
  unsigned char* dst = wbf + ((size_t)((tap * 2 + oblk) * 8 + iblk)) * WTILEB;
  for (int t = threadIdx.x; t < 512; t += 256) {
    int oo = t >> 2, c = t & 3;
    int cp = c ^ ((oo >> 1) & 3);
    int o = oblk * 128 + oo;
    bf16x8 v;
#pragma unroll
    for (int j = 0; j < 8; ++j) {
      int i = iblk * 32 + c * 8 + j;
      v[j] = (short)f2bf(weight[((size_t)o * IN_C + i) * 9 + tap]);
    }
    *(bf16x8*)(dst + oo * 64 + cp * 16) = v;
  }
}

// ---- kernel 4: pack X' = bf16(x*s), [b][iblk][row][130 slots][32 i], ------
// slot 0 / 129 are zero guards (W-padding); chunks XOR-swizzled.
__global__ void xpack_kernel(const float* __restrict__ x,
                             const float* __restrict__ s_in,
                             unsigned char* __restrict__ xp) {
  int row = blockIdx.x, iblk = blockIdx.y, b = blockIdx.z;
  const float* xb = x + ((size_t)(b * IN_C + iblk * 32)) * HW + row * W_IMG;
  const float* sb = s_in + b * IN_C + iblk * 32;
  unsigned char* dst = xp + ((size_t)((b * 8 + iblk) * 128 + row)) * XROWB;
  for (int t = threadIdx.x; t < 520; t += 256) {
    int slot = t >> 2, c = t & 3;
    int cp = c ^ ((slot >> 1) & 3);
    int pix = slot - 1;
    bf16x8 v = (bf16x8)(short)0;
    if ((unsigned)pix < 128u) {
#pragma unroll
      for (int j = 0; j < 8; ++j) {
        int ii = c * 8 + j;
        float xv = xb[(size_t)ii * HW + pix];
        v[j] = (short)f2bf(xv * sb[ii]);
      }
    }
    *(bf16x8*)(dst + slot * 64 + cp * 16) = v;
  }
}

// ---- kernel 5: conv GEMM ---------------------------------------------------
// grid (h=128, oblk=2, b=8), block 256 = 4 waves (2 o x 2 pix).
// Block tile: 128 o x 128 pix (one image row). Wave tile 64x64 (4x4 frags).
// Phase (kh, i0): stage Xs[130][32] + As[3 kw][128][32] via global_load_lds,
// then 3 kw x (4 A-reads + 4 B-reads + 16 MFMA) per wave.
__global__ __launch_bounds__(256, 4) void modconv_kernel(
    const unsigned char* __restrict__ xp, const unsigned char* __restrict__ wbf,
    const float* __restrict__ dscaled, float* __restrict__ out) {
  __shared__ __align__(16) unsigned char lds[XROWB + 3 * WTILEB];  // 32896 B

  const int tid = threadIdx.x;
  const int lane = tid & 63;
  const int wv = tid >> 6;
  const int wr = wv >> 1, wc = wv & 1;
  const int h = blockIdx.x;
  const int oblk = blockIdx.y;
  const int b = blockIdx.z;
  const int l15 = lane & 15, cc = lane >> 4;

  f32x4 acc[4][4] = {};

  // A fragment offsets: row = wr*64 + m*16 + l15; (row>>1)&3 == (l15>>1)&3.
  const int axor = ((cc ^ ((l15 >> 1) & 3)) << 4);
  int aoff[4];
#pragma unroll
  for (int m = 0; m < 4; ++m)
    aoff[m] = XROWB + (wr * 64 + m * 16 + l15) * 64 + axor;

  for (int kh = 0; kh < 3; ++kh) {
    const int row = h + kh - 1;
    if ((unsigned)row >= 128u) continue;  // vertical zero-pad: skip (uniform)
    for (int i0 = 0; i0 < 8; ++i0) {
      const unsigned char* xsrc =
          xp + ((size_t)((b * 8 + i0) * 128 + row)) * XROWB;
      // ---- stage 33 x 1KB-ish chunks across 4 waves
      for (int tsk = wv; tsk < 33; tsk += 4) {
        if (tsk < 24) {
          int kw = tsk >> 3, ch = tsk & 7;
          const unsigned char* g =
              wbf + ((size_t)(((kh * 3 + kw) * 2 + oblk) * 8 + i0)) * WTILEB +
              ch * 1024 + lane * 16;
          glds16(g, lds + XROWB + kw * WTILEB + ch * 1024);
        } else if (tsk < 32) {
          int ch = tsk - 24;
          glds16(xsrc + ch * 1024 + lane * 16, lds + ch * 1024);
        } else if (lane < 8) {  // Xs remainder: 130*64 - 8192 = 128 B
          glds16(xsrc + 8192 + lane * 16, lds + 8192);
        }
      }
      asm volatile("s_waitcnt vmcnt(0)" ::: "memory");
      __syncthreads();
      // ---- compute 3 kw taps
#pragma unroll
      for (int kw = 0; kw < 3; ++kw) {
        bf16x8 a0 = *(const bf16x8*)(lds + kw * WTILEB + aoff[0]);
        bf16x8 a1 = *(const bf16x8*)(lds + kw * WTILEB + aoff[1]);
        bf16x8 a2 = *(const bf16x8*)(lds + kw * WTILEB + aoff[2]);
        bf16x8 a3 = *(const bf16x8*)(lds + kw * WTILEB + aoff[3]);
        const int bb0 = (wc * 64 + l15 + kw) * 64 +
                        ((cc ^ (((l15 + kw) >> 1) & 3)) << 4);
        __builtin_amdgcn_s_setprio(1);
#pragma unroll
        for (int n = 0; n < 4; ++n) {
          bf16x8 bn = *(const bf16x8*)(lds + bb0 + n * 1024);
          acc[0][n] = __builtin_amdgcn_mfma_f32_16x16x32_bf16(a0, bn, acc[0][n], 0, 0, 0);
          acc[1][n] = __builtin_amdgcn_mfma_f32_16x16x32_bf16(a1, bn, acc[1][n], 0, 0, 0);
          acc[2][n] = __builtin_amdgcn_mfma_f32_16x16x32_bf16(a2, bn, acc[2][n], 0, 0, 0);
          acc[3][n] = __builtin_amdgcn_mfma_f32_16x16x32_bf16(a3, bn, acc[3][n], 0, 0, 0);
        }
        __builtin_amdgcn_s_setprio(0);
      }
      __syncthreads();
    }
  }

  // ---- epilogue: demod scale + LeakyReLU + coalesced store
  const float* db = dscaled + b * OUT_C + oblk * 128;
  float* ob = out + (((size_t)(b * OUT_C + oblk * 128)) << 14);
  const int pixb = h * 128 + wc * 64 + l15;
#pragma unroll
  for (int m = 0; m < 4; ++m) {
#pragma unroll
    for (int r = 0; r < 4; ++r) {
      int oo = wr * 64 + m * 16 + cc * 4 + r;
      float d = db[oo];
#pragma unroll
      for (int n = 0; n < 4; ++n) {
        float v = acc[m][n][r] * d;
        v = (v >= 0.f) ? v : NEG_SLOPE * v;
        ob[((size_t)oo << 14) + pixb + n * 16] = v;
      }
    }
  }
}

// ---- launcher ---------------------------------------------------------------
extern "C" void kernel_launch(void* const* d_in, const int* in_sizes, int n_in,
                              void* d_out, int out_size, void* d_ws,
                              size_t ws_size, hipStream_t stream) {
  const float* x = (const float*)d_in[0];      // [8,256,128,128]
  const float* style = (const float*)d_in[1];  // [8,512]
  const float* weight = (const float*)d_in[2]; // [256,256,3,3]
  const float* mod_w = (const float*)d_in[3];  // [256,512]
  const float* mod_b = (const float*)d_in[4];  // [256]
  float* out = (float*)d_out;                  // [8,256,128,128]

  float* s_ws = (float*)d_ws;                        // 8KB
  float* dsc = s_ws + 2048;                          // 8KB
  unsigned char* wbf = (unsigned char*)d_ws + 16384; // 1.125 MB
  unsigned char* xp = wbf + (size_t)9 * 2 * 8 * WTILEB;  // 65 MB

  style_mod_kernel<<<dim3(8), dim3(256), 0, stream>>>(style, mod_w, mod_b, s_ws);
  demod_kernel<<<dim3(8 * OUT_C), dim3(256), 0, stream>>>(weight, s_ws, dsc);
  wpack_kernel<<<dim3(9, 2, 8), dim3(256), 0, stream>>>(weight, wbf);
  xpack_kernel<<<dim3(128, 8, 8), dim3(256), 0, stream>>>(x, s_ws, xp);

  modconv_kernel<<<dim3(128, 2, 8), dim3(256), 0, stream>>>(xp, wbf, dsc, out);
}